// Round 1
// baseline (351.748 us; speedup 1.0000x reference)
//
#include <hip/hip_runtime.h>
#include <hip/hip_bf16.h>

typedef __attribute__((ext_vector_type(4))) float f32x4;
typedef __attribute__((ext_vector_type(8))) short s16x8;
typedef unsigned short u16;

#define B_SZ   128
#define T_SZ   256
#define C_SZ   512
#define H_SZ   8
#define HD_SZ  64

__device__ __forceinline__ u16 f2bf(float f) {
    union { float f; unsigned int u; } a; a.f = f;
    unsigned int u = a.u;
    unsigned int lsb = (u >> 16) & 1u;
    u += 0x7fffu + lsb;               // round-to-nearest-even
    return (u16)(u >> 16);
}

// ---------------- conversion kernels ----------------

__global__ void cvt_x_kernel(const float* __restrict__ x, u16* __restrict__ xb, int n4) {
    int i = blockIdx.x * 256 + threadIdx.x;
    if (i < n4) {
        float4 v = ((const float4*)x)[i];
        ushort4 o;
        o.x = f2bf(v.x); o.y = f2bf(v.y); o.z = f2bf(v.z); o.w = f2bf(v.w);
        ((ushort4*)xb)[i] = o;
    }
}

template<int KK, int NN>
__global__ void cvt_wT_kernel(const float* __restrict__ w, u16* __restrict__ wt) {
    int i = blockIdx.x * 256 + threadIdx.x;
    if (i < KK * NN) {
        int k = i / NN, n = i % NN;          // w is [KK][NN] row-major
        wt[n * KK + k] = f2bf(w[i]);         // wt is [NN][KK]
    }
}

// ---------------- GEMM mainloop (128x128 tile, BK=64, bf16 MFMA) ----------------
// A: [M][K] bf16 row-major; Bt: [N][K] bf16 row-major (i.e. B transposed).
// LDS rows padded to 72 shorts (144 B, 16B-aligned; 36 dwords stride => 2-way bank alias, free).

template<int K>
__device__ __forceinline__ void gemm_tile(const u16* __restrict__ A, const u16* __restrict__ Bt,
                                          int m0, int n0, u16* As, u16* Bs, f32x4 (&acc)[4][4]) {
    const int tid  = threadIdx.x;
    const int lane = tid & 63, li = lane & 15, quad = lane >> 4;
    const int wave = tid >> 6;
    const int wm = (wave & 1) * 64, wn = (wave >> 1) * 64;
    for (int kt = 0; kt < K; kt += 64) {
        for (int c = tid; c < 1024; c += 256) {
            int row = c >> 3, ch = c & 7;
            *(int4*)&As[row * 72 + ch * 8] = *(const int4*)&A[(m0 + row) * K + kt + ch * 8];
            *(int4*)&Bs[row * 72 + ch * 8] = *(const int4*)&Bt[(n0 + row) * K + kt + ch * 8];
        }
        __syncthreads();
#pragma unroll
        for (int kk = 0; kk < 64; kk += 32) {
            s16x8 af[4], bfr[4];
#pragma unroll
            for (int i = 0; i < 4; ++i)
                af[i] = *(const s16x8*)&As[(wm + i * 16 + li) * 72 + kk + quad * 8];
#pragma unroll
            for (int i = 0; i < 4; ++i)
                bfr[i] = *(const s16x8*)&Bs[(wn + i * 16 + li) * 72 + kk + quad * 8];
#pragma unroll
            for (int i = 0; i < 4; ++i)
#pragma unroll
                for (int j = 0; j < 4; ++j)
                    acc[i][j] = __builtin_amdgcn_mfma_f32_16x16x32_bf16(af[i], bfr[j], acc[i][j], 0, 0, 0);
        }
        __syncthreads();
    }
}

// ---------------- GEMM1: qkv = x @ W_qkv + b_qkv, scatter into Q/K/V [B,H,T,64] bf16 ----------------

__global__ __launch_bounds__(256) void gemm_qkv_kernel(const u16* __restrict__ xb,
                                                       const u16* __restrict__ WqkvT,
                                                       const float* __restrict__ b_qkv,
                                                       u16* __restrict__ Qb, u16* __restrict__ Kb,
                                                       u16* __restrict__ Vb) {
    __shared__ __align__(16) u16 As[128 * 72];
    __shared__ __align__(16) u16 Bs[128 * 72];
    f32x4 acc[4][4];
#pragma unroll
    for (int i = 0; i < 4; ++i)
#pragma unroll
        for (int j = 0; j < 4; ++j) acc[i][j] = {0.f, 0.f, 0.f, 0.f};
    const int m0 = blockIdx.y * 128, n0 = blockIdx.x * 128;
    gemm_tile<512>(xb, WqkvT, m0, n0, As, Bs, acc);

    const int tid = threadIdx.x, lane = tid & 63, li = lane & 15, quad = lane >> 4, wave = tid >> 6;
    const int wm = (wave & 1) * 64, wn = (wave >> 1) * 64;
#pragma unroll
    for (int j = 0; j < 4; ++j) {
        int col = n0 + wn + j * 16 + li;          // 0..1535
        float bias = b_qkv[col];
        int which = col >> 9, hh = (col >> 6) & 7, dd = col & 63;
        u16* dst = (which == 0) ? Qb : ((which == 1) ? Kb : Vb);
#pragma unroll
        for (int i = 0; i < 4; ++i)
#pragma unroll
            for (int r = 0; r < 4; ++r) {
                int row = m0 + wm + i * 16 + quad * 4 + r;   // 0..32767
                int bb = row >> 8, tt = row & 255;
                dst[((bb * 8 + hh) << 14) + tt * 64 + dd] = f2bf(acc[i][j][r] + bias);
            }
    }
}

// ---------------- GEMM2: out = Yb @ W_out + b_out (fp32 out) ----------------

__global__ __launch_bounds__(256) void gemm_out_kernel(const u16* __restrict__ Yb,
                                                       const u16* __restrict__ WoutT,
                                                       const float* __restrict__ b_out,
                                                       float* __restrict__ out) {
    __shared__ __align__(16) u16 As[128 * 72];
    __shared__ __align__(16) u16 Bs[128 * 72];
    f32x4 acc[4][4];
#pragma unroll
    for (int i = 0; i < 4; ++i)
#pragma unroll
        for (int j = 0; j < 4; ++j) acc[i][j] = {0.f, 0.f, 0.f, 0.f};
    const int m0 = blockIdx.y * 128, n0 = blockIdx.x * 128;
    gemm_tile<512>(Yb, WoutT, m0, n0, As, Bs, acc);

    const int tid = threadIdx.x, lane = tid & 63, li = lane & 15, quad = lane >> 4, wave = tid >> 6;
    const int wm = (wave & 1) * 64, wn = (wave >> 1) * 64;
#pragma unroll
    for (int j = 0; j < 4; ++j) {
        int col = n0 + wn + j * 16 + li;
        float bias = b_out[col];
#pragma unroll
        for (int i = 0; i < 4; ++i)
#pragma unroll
            for (int r = 0; r < 4; ++r) {
                int row = m0 + wm + i * 16 + quad * 4 + r;
                out[row * 512 + col] = acc[i][j][r] + bias;
            }
    }
}

// ---------------- attention: one workgroup per (b, h, 64 q-rows); wave = 16 q-rows ----------------
// Full 16x256 score rows live in 16 MFMA accumulators per wave (no online softmax at T=256).
// kv LDS union: K-half [128][72] (9216 u16) / Vt-half [64][136] (8704 u16).

__global__ __launch_bounds__(256) void attn_kernel(const u16* __restrict__ Qb,
                                                   const u16* __restrict__ Kb,
                                                   const u16* __restrict__ Vb,
                                                   u16* __restrict__ Yb) {
    __shared__ __align__(16) u16 kv[128 * 72];
    __shared__ __align__(16) u16 pl[4 * 16 * 264];

    const int tid = threadIdx.x, wave = tid >> 6, lane = tid & 63, li = lane & 15, quad = lane >> 4;
    const int b = blockIdx.z, h = blockIdx.y, qt = blockIdx.x;
    const int bh = (b * 8 + h) << 14;          // *T*64 elements
    const int q0 = qt * 64, qrb = q0 + wave * 16;
    const int nst = (qrb >> 4) + 1;            // number of valid 16-wide s-tiles for this wave

    // Q fragments (A-operand): A[m=li][k=quad*8+j], two k-chunks of 32
    s16x8 qf0 = *(const s16x8*)&Qb[bh + (qrb + li) * 64 + quad * 8];
    s16x8 qf1 = *(const s16x8*)&Qb[bh + (qrb + li) * 64 + 32 + quad * 8];

    f32x4 sacc[16];
#pragma unroll
    for (int st = 0; st < 16; ++st) sacc[st] = {0.f, 0.f, 0.f, 0.f};

    // ---- S = Q K^T : half 0 (s in [0,128)) ----
    for (int c = tid; c < 1024; c += 256) {
        int row = c >> 3, ch = c & 7;
        *(int4*)&kv[row * 72 + ch * 8] = *(const int4*)&Kb[bh + row * 64 + ch * 8];
    }
    __syncthreads();
    const int lim0 = nst < 8 ? nst : 8;
#pragma unroll
    for (int st = 0; st < 8; ++st) {
        if (st < lim0) {
            s16x8 b0 = *(const s16x8*)&kv[(st * 16 + li) * 72 + quad * 8];
            s16x8 b1 = *(const s16x8*)&kv[(st * 16 + li) * 72 + 32 + quad * 8];
            sacc[st] = __builtin_amdgcn_mfma_f32_16x16x32_bf16(qf0, b0, sacc[st], 0, 0, 0);
            sacc[st] = __builtin_amdgcn_mfma_f32_16x16x32_bf16(qf1, b1, sacc[st], 0, 0, 0);
        }
    }
    __syncthreads();
    if (q0 >= 128) {   // block-uniform
        for (int c = tid; c < 1024; c += 256) {
            int row = c >> 3, ch = c & 7;
            *(int4*)&kv[row * 72 + ch * 8] = *(const int4*)&Kb[bh + (128 + row) * 64 + ch * 8];
        }
        __syncthreads();
#pragma unroll
        for (int st = 8; st < 16; ++st) {
            if (st < nst) {
                int srow = (st * 16 - 128 + li) * 72;
                s16x8 b0 = *(const s16x8*)&kv[srow + quad * 8];
                s16x8 b1 = *(const s16x8*)&kv[srow + 32 + quad * 8];
                sacc[st] = __builtin_amdgcn_mfma_f32_16x16x32_bf16(qf0, b0, sacc[st], 0, 0, 0);
                sacc[st] = __builtin_amdgcn_mfma_f32_16x16x32_bf16(qf1, b1, sacc[st], 0, 0, 0);
            }
        }
        __syncthreads();
    }

    // ---- softmax over the full row (scale 1/sqrt(64)=0.125, causal mask) ----
    float mx[4] = {-3e38f, -3e38f, -3e38f, -3e38f};
#pragma unroll
    for (int st = 0; st < 16; ++st) {
        if (st < nst) {
            int sg = st * 16 + li;
#pragma unroll
            for (int r = 0; r < 4; ++r) {
                int tg = qrb + quad * 4 + r;
                float v = (sg <= tg) ? sacc[st][r] * 0.125f : -3e38f;
                sacc[st][r] = v;
                mx[r] = fmaxf(mx[r], v);
            }
        }
    }
#pragma unroll
    for (int d = 1; d < 16; d <<= 1)
#pragma unroll
        for (int r = 0; r < 4; ++r) mx[r] = fmaxf(mx[r], __shfl_xor(mx[r], d, 64));

    float l[4] = {0.f, 0.f, 0.f, 0.f};
    const int ns32 = (nst + 1) >> 1;           // number of 32-wide PV chunks
    const int nstw = ns32 * 2;                 // tiles to write into pl (zero-pad odd tail)
#pragma unroll
    for (int st = 0; st < 16; ++st) {
        if (st < nstw) {
#pragma unroll
            for (int r = 0; r < 4; ++r) {
                float e = (st < nst) ? __expf(sacc[st][r] - mx[r]) : 0.f;
                l[r] += e;
                pl[wave * 4224 + (quad * 4 + r) * 264 + st * 16 + li] = f2bf(e);
            }
        }
    }
#pragma unroll
    for (int d = 1; d < 16; d <<= 1)
#pragma unroll
        for (int r = 0; r < 4; ++r) l[r] += __shfl_xor(l[r], d, 64);

    // ---- O = P V : half 0 (s in [0,128)), V transposed into LDS [d][s] ----
    f32x4 oacc[4];
#pragma unroll
    for (int dt = 0; dt < 4; ++dt) oacc[dt] = {0.f, 0.f, 0.f, 0.f};

    for (int c = tid; c < 1024; c += 256) {
        int sl = c >> 3, dch = c & 7;
        int4 w = *(const int4*)&Vb[bh + sl * 64 + dch * 8];
        const u16* wsv = (const u16*)&w;
#pragma unroll
        for (int e = 0; e < 8; ++e) kv[(dch * 8 + e) * 136 + sl] = wsv[e];
    }
    __syncthreads();
    const int limc0 = ns32 < 4 ? ns32 : 4;
#pragma unroll
    for (int c = 0; c < 4; ++c) {
        if (c < limc0) {
            s16x8 pf = *(const s16x8*)&pl[wave * 4224 + li * 264 + c * 32 + quad * 8];
#pragma unroll
            for (int dt = 0; dt < 4; ++dt) {
                s16x8 vf = *(const s16x8*)&kv[(dt * 16 + li) * 136 + c * 32 + quad * 8];
                oacc[dt] = __builtin_amdgcn_mfma_f32_16x16x32_bf16(pf, vf, oacc[dt], 0, 0, 0);
            }
        }
    }
    __syncthreads();
    if (q0 >= 128) {
        for (int c = tid; c < 1024; c += 256) {
            int sl = c >> 3, dch = c & 7;
            int4 w = *(const int4*)&Vb[bh + (128 + sl) * 64 + dch * 8];
            const u16* wsv = (const u16*)&w;
#pragma unroll
            for (int e = 0; e < 8; ++e) kv[(dch * 8 + e) * 136 + sl] = wsv[e];
        }
        __syncthreads();
#pragma unroll
        for (int c = 4; c < 8; ++c) {
            if (c < ns32) {
                s16x8 pf = *(const s16x8*)&pl[wave * 4224 + li * 264 + c * 32 + quad * 8];
#pragma unroll
                for (int dt = 0; dt < 4; ++dt) {
                    s16x8 vf = *(const s16x8*)&kv[(dt * 16 + li) * 136 + (c * 32 - 128) + quad * 8];
                    oacc[dt] = __builtin_amdgcn_mfma_f32_16x16x32_bf16(pf, vf, oacc[dt], 0, 0, 0);
                }
            }
        }
    }

    // ---- epilogue: Yb[b,t, h*64+d] = O / l ----
    float inv[4];
#pragma unroll
    for (int r = 0; r < 4; ++r) inv[r] = 1.0f / l[r];
#pragma unroll
    for (int dt = 0; dt < 4; ++dt)
#pragma unroll
        for (int r = 0; r < 4; ++r) {
            int tg = qrb + quad * 4 + r;
            Yb[(b * 256 + tg) * 512 + h * 64 + dt * 16 + li] = f2bf(oacc[dt][r] * inv[r]);
        }
}

// ---------------- launch ----------------

extern "C" void kernel_launch(void* const* d_in, const int* in_sizes, int n_in,
                              void* d_out, int out_size, void* d_ws, size_t ws_size,
                              hipStream_t stream) {
    const float* x     = (const float*)d_in[0];
    const float* W_qkv = (const float*)d_in[1];
    const float* b_qkv = (const float*)d_in[2];
    const float* W_out = (const float*)d_in[3];
    const float* b_out = (const float*)d_in[4];
    float* out = (float*)d_out;

    char* ws = (char*)d_ws;
    // workspace layout (bytes, 16B-aligned):
    u16* Qb    = (u16*)(ws);                       //  33,554,432
    u16* Kb    = (u16*)(ws + 33554432);            //  33,554,432
    u16* Vb    = (u16*)(ws + 67108864);            //  33,554,432
    u16* WqkvT = (u16*)(ws + 100663296);           //   1,572,864
    u16* WoutT = (u16*)(ws + 102236160);           //     524,288
    u16* xb    = (u16*)(ws + 102760448);           //  33,554,432 (reused as Yb after GEMM1)
    u16* Yb    = xb;
    if (ws_size < (size_t)136314880) return;       // need ~130 MB scratch

    cvt_x_kernel<<<16384, 256, 0, stream>>>(x, xb, 4194304);
    cvt_wT_kernel<512, 1536><<<3072, 256, 0, stream>>>(W_qkv, WqkvT);
    cvt_wT_kernel<512, 512><<<1024, 256, 0, stream>>>(W_out, WoutT);
    gemm_qkv_kernel<<<dim3(12, 256), 256, 0, stream>>>(xb, WqkvT, b_qkv, Qb, Kb, Vb);
    attn_kernel<<<dim3(4, 8, 128), 256, 0, stream>>>(Qb, Kb, Vb, Yb);
    gemm_out_kernel<<<dim3(4, 256), 256, 0, stream>>>(Yb, WoutT, b_out, out);
}